// Round 3
// baseline (177.123 us; speedup 1.0000x reference)
//
#include <hip/hip_runtime.h>
#include <hip/hip_bf16.h>

#define BATCH 8192
#define IN 128
#define OUT 128
#define NB 18
#define ROW (IN * NB)           // 2304 floats per output row of cf
#define CFT_ELEMS (ROW * OUT)   // 294912
#define BT 16                   // batch rows per block
#define THREADS 256
#define NBLK (BATCH / BT)       // 512

// Transpose cf[o][i*18+k] (o-major) -> cfT[i*18+k][o] so the main kernel's
// per-tap reads are lane-coalesced (o varies across lanes).
__global__ __launch_bounds__(THREADS) void repack_kernel(
    const float* __restrict__ cf, float* __restrict__ cfT)
{
    int tid = blockIdx.x * THREADS + threadIdx.x;   // 0 .. 294911
    int ik = tid >> 7;         // i*18 + k
    int o  = tid & 127;
    cfT[tid] = cf[o * ROW + ik];   // coalesced write, scattered read (one-off 1.18 MB)
}

template <bool USE_T>
__global__ __launch_bounds__(THREADS, 2) void kan_main(
    const float* __restrict__ x,     // [BATCH][IN] fp32
    const float* __restrict__ cfa,   // USE_T ? cfT[ik][o] : cf[o][ik]
    float* __restrict__ out)         // [BATCH][OUT] fp32
{
    __shared__ float4        s_w[BT][IN];   // 32 KB: per-(b,i) 4 spline weights
    __shared__ unsigned char s_m[BT][IN];   // window start m in [0,14]
    __shared__ float         s_xs[BT];      // per-b sum of tanh(x)

    const int t    = threadIdx.x;
    const int boff = blockIdx.x * BT;

    // ---------- Phase A: cardinal cubic B-spline weights + tanh row sums ----
    {
        const int b  = t >> 4;   // 0..15
        const int il = t & 15;
        float xs = 0.f;
        #pragma unroll
        for (int k = 0; k < IN / 16; ++k) {
            int i = il + 16 * k;
            float xf = x[(boff + b) * IN + i];
            float xt = tanhf(xf);
            xs += xt;
            float s = (xt + 1.0f) * 7.5f;      // (xt+1)/h, h = 2/15
            int m = (int)s;                    // interior cell, 0..14
            m = m < 0 ? 0 : (m > 14 ? 14 : m);
            float u  = s - (float)m;           // [0,1)
            float om = 1.0f - u;
            float u2 = u * u;
            float w0 = (1.0f / 6.0f) * om * om * om;
            float w1 = (2.0f / 3.0f) - u2 * (1.0f - 0.5f * u);
            float w2 = (1.0f / 6.0f) + 0.5f * (u + u2 - u2 * u);
            float w3 = (1.0f / 6.0f) * u * u2;
            s_w[b][i] = make_float4(w0, w1, w2, w3);
            s_m[b][i] = (unsigned char)m;
        }
        for (int d = 8; d > 0; d >>= 1) xs += __shfl_down(xs, d, 16);
        if (il == 0) s_xs[b] = xs;
    }
    __syncthreads();

    // ---------- Phase B: 4-sparse contraction, wave-uniform b ----------
    // wave w owns b = 4w + r (r=0..3); lane l owns outputs o = 2l, 2l+1.
    const int w = t >> 6;
    const int l = t & 63;

    #pragma unroll
    for (int r = 0; r < 4; ++r) {
        const int b = w * 4 + r;
        float a0 = 0.f, a0b = 0.f, a1 = 0.f, a1b = 0.f;
        for (int i = 0; i < IN; ++i) {
            float4 wv = s_w[b][i];          // wave-uniform LDS broadcast
            int    m  = (int)s_m[b][i];
            if (USE_T) {
                // 4 taps = 4 coalesced 512B rows of cfT
                const float2* p = (const float2*)(cfa + (i * NB + m) * OUT) + l;
                float2 c0 = p[0];
                float2 c1 = p[64];    // +128 floats = next tap row
                float2 c2 = p[128];
                float2 c3 = p[192];
                a0  += wv.x * c0.x + wv.y * c1.x;
                a0b += wv.z * c2.x + wv.w * c3.x;
                a1  += wv.x * c0.y + wv.y * c1.y;
                a1b += wv.z * c2.y + wv.w * c3.y;
            } else {
                // fallback: original o-major layout (used only if ws too small)
                const float* p0 = cfa + (2 * l) * ROW + i * NB + m;
                const float* p1 = p0 + ROW;
                a0  += wv.x * p0[0] + wv.y * p0[1];
                a0b += wv.z * p0[2] + wv.w * p0[3];
                a1  += wv.x * p1[0] + wv.y * p1[1];
                a1b += wv.z * p1[2] + wv.w * p1[3];
            }
        }
        float xsv = s_xs[b];
        float2 st;
        st.x = (xsv + a0 + a0b) * (1.0f / 128.0f);   // o = 2l
        st.y = (xsv + a1 + a1b) * (1.0f / 128.0f);   // o = 2l+1
        ((float2*)out)[(boff + b) * (OUT / 2) + l] = st;  // coalesced 8B/lane fp32 store
    }
}

extern "C" void kernel_launch(void* const* d_in, const int* in_sizes, int n_in,
                              void* d_out, int out_size, void* d_ws, size_t ws_size,
                              hipStream_t stream) {
    const float* x  = (const float*)d_in[0];
    const float* cf = (const float*)d_in[1];
    float* out = (float*)d_out;
    if (ws_size >= (size_t)CFT_ELEMS * sizeof(float)) {
        float* cfT = (float*)d_ws;
        repack_kernel<<<CFT_ELEMS / THREADS, THREADS, 0, stream>>>(cf, cfT);
        kan_main<true><<<NBLK, THREADS, 0, stream>>>(x, cfT, out);
    } else {
        kan_main<false><<<NBLK, THREADS, 0, stream>>>(x, cf, out);
    }
}

// Round 4
// 85.425 us; speedup vs baseline: 2.0734x; 2.0734x over previous
//
#include <hip/hip_runtime.h>

#define BATCH 8192
#define IN 128
#define OUT 128
#define NB 18
#define ROW (IN * NB)          // 2304
#define CF_ELEMS (OUT * ROW)   // 294912
#define MT 32                  // batch rows per block
#define KC 288                 // K-chunk = 16 i-groups * 18
#define AROW 296               // KC + 8 bf16 pad -> 592 B row (16B-aligned, 148 dw = 20 mod 32)
#define NCH 8                  // 2304 / 288

typedef short  bf16x8 __attribute__((ext_vector_type(8)));
typedef float  f32x16 __attribute__((ext_vector_type(16)));

static __device__ __forceinline__ unsigned short f2bf(float f) {
    union { float f; unsigned u; } v; v.f = f;
    unsigned r = v.u + 0x7fffu + ((v.u >> 16) & 1u);   // RNE
    return (unsigned short)(r >> 16);
}
static __device__ __forceinline__ bf16x8 as_bf16x8(uint4 v) {
    union { uint4 u; bf16x8 b; } x; x.u = v; return x.b;
}

// cf fp32 [o][ik] -> bf16 [o][ik] (same layout; o-major IS the MFMA B-fragment layout)
__global__ __launch_bounds__(256) void cvt_kernel(const float4* __restrict__ cf,
                                                  ushort4* __restrict__ cfb) {
    int tid = blockIdx.x * 256 + threadIdx.x;    // 0 .. 73727, fully coalesced
    float4 v = cf[tid];
    ushort4 o;
    o.x = f2bf(v.x); o.y = f2bf(v.y); o.z = f2bf(v.z); o.w = f2bf(v.w);
    cfb[tid] = o;
}

__global__ __launch_bounds__(256) void kan_mfma(const float* __restrict__ x,
                                                const unsigned short* __restrict__ cfb,
                                                float* __restrict__ out) {
    __shared__ unsigned short sA[MT][AROW];   // 18.9 KB basis tile (bf16)
    __shared__ float s_xs[MT];

    const int t  = threadIdx.x;
    const int w  = t >> 6;          // wave 0..3 -> N-slice 32w
    const int l  = t & 63;
    const int b0 = blockIdx.x * MT;

    const int ab = t >> 3;          // A-build row b (0..31)
    const int iq = t & 7;

    // B-operand pointer: lane holds B[k][n=o] for o = 32w + (l&31), k = 8*(l>>5)+j
    const int o  = (w << 5) + (l & 31);
    const int kb = (l >> 5) << 3;
    const uint4* bptr = (const uint4*)(cfb + o * ROW + kb);   // 16B-aligned

    f32x16 acc;
    #pragma unroll
    for (int r = 0; r < 16; ++r) acc[r] = 0.f;
    float xs = 0.f;

    for (int c = 0; c < NCH; ++c) {
        // ---- prefetch this chunk's 18 B-fragments (independent of LDS) ----
        uint4 Bf[18];
        #pragma unroll
        for (int s = 0; s < 18; ++s)
            Bf[s] = bptr[c * 36 + 2 * s];    // (c*288 + 16s)/8 uint4s

        __syncthreads();   // prior chunk's A-fragment reads complete

        // ---- build A-tile: 2 cells (b=ab, i=16c+iq, 16c+iq+8), 18 cols each ----
        #pragma unroll
        for (int h = 0; h < 2; ++h) {
            int il = iq + (h << 3);                 // 0..15
            int i  = (c << 4) + il;
            float xt = tanhf(x[(b0 + ab) * IN + i]);
            xs += xt;
            float s = (xt + 1.0f) * 7.5f;           // (xt+1)/h, h=2/15
            int m = (int)s; m = m < 0 ? 0 : (m > 14 ? 14 : m);
            float u = s - (float)m, om = 1.f - u, u2 = u * u;
            float w0 = (1.f / 6.f) * om * om * om;
            float w1 = (2.f / 3.f) - u2 * (1.f - 0.5f * u);
            float w2 = (1.f / 6.f) + 0.5f * (u + u2 - u2 * u);
            float w3 = (1.f / 6.f) * u * u2;
            // 4 bf16 taps at positions m..m+3 of an 18-col cell, rest zeros.
            unsigned lo = (unsigned)f2bf(w0) | ((unsigned)f2bf(w1) << 16);
            unsigned hi = (unsigned)f2bf(w2) | ((unsigned)f2bf(w3) << 16);
            int odd = m & 1;
            unsigned t0 = odd ? (lo << 16) : lo;
            unsigned t1 = odd ? ((hi << 16) | (lo >> 16)) : hi;
            unsigned t2 = odd ? (hi >> 16) : 0u;
            int dq = m >> 1;                        // 0..7
            unsigned* dst = (unsigned*)(&sA[ab][0] + il * 18);  // 36B cell, dword-aligned
            #pragma unroll
            for (int j = 0; j < 9; ++j) {
                unsigned v = (j == dq) ? t0 : (j == dq + 1) ? t1
                           : (j == dq + 2) ? t2 : 0u;
                dst[j] = v;
            }
        }
        __syncthreads();

        // ---- 18 MFMA steps over this K-chunk ----
        #pragma unroll
        for (int s = 0; s < 18; ++s) {
            uint4 av = *(const uint4*)(&sA[l & 31][(s << 4) + kb]);  // ds_read_b128
            acc = __builtin_amdgcn_mfma_f32_32x32x16_bf16(
                      as_bf16x8(av), as_bf16x8(Bf[s]), acc, 0, 0, 0);
        }
    }

    // ---- tanh row sums: 8 consecutive lanes share b=ab ----
    xs += __shfl_down(xs, 4, 8);
    xs += __shfl_down(xs, 2, 8);
    xs += __shfl_down(xs, 1, 8);
    if (iq == 0) s_xs[ab] = xs;
    __syncthreads();

    // ---- epilogue: C/D layout col=l&31, row=(r&3)+8*(r>>2)+4*(l>>5) ----
    #pragma unroll
    for (int r = 0; r < 16; ++r) {
        int row = (r & 3) + ((r >> 2) << 3) + ((l >> 5) << 2);
        int col = l & 31;
        out[(b0 + row) * OUT + (w << 5) + col] =
            (s_xs[row] + acc[r]) * (1.0f / 128.0f);
    }
}

// ---------------- fallback (ws too small): R3's proven VALU kernel ----------------
__global__ __launch_bounds__(256, 2) void kan_valu(const float* __restrict__ x,
                                                   const float* __restrict__ cf,
                                                   float* __restrict__ out) {
    __shared__ float4        s_w[16][IN];
    __shared__ unsigned char s_m[16][IN];
    __shared__ float         s_xs[16];
    const int t = threadIdx.x;
    const int boff = blockIdx.x * 16;
    {
        const int b = t >> 4, il = t & 15;
        float xs = 0.f;
        #pragma unroll
        for (int k = 0; k < IN / 16; ++k) {
            int i = il + 16 * k;
            float xt = tanhf(x[(boff + b) * IN + i]);
            xs += xt;
            float s = (xt + 1.0f) * 7.5f;
            int m = (int)s; m = m < 0 ? 0 : (m > 14 ? 14 : m);
            float u = s - (float)m, om = 1.f - u, u2 = u * u;
            s_w[b][i] = make_float4((1.f/6.f)*om*om*om,
                                    (2.f/3.f) - u2*(1.f - 0.5f*u),
                                    (1.f/6.f) + 0.5f*(u + u2 - u2*u),
                                    (1.f/6.f)*u*u2);
            s_m[b][i] = (unsigned char)m;
        }
        for (int d = 8; d > 0; d >>= 1) xs += __shfl_down(xs, d, 16);
        if (il == 0) s_xs[b] = xs;
    }
    __syncthreads();
    const int w = t >> 6, l = t & 63;
    #pragma unroll
    for (int r = 0; r < 4; ++r) {
        const int b = w * 4 + r;
        float a0 = 0.f, a1 = 0.f;
        for (int i = 0; i < IN; ++i) {
            float4 wv = s_w[b][i];
            int m = (int)s_m[b][i];
            const float* p0 = cf + (2 * l) * ROW + i * NB + m;
            const float* p1 = p0 + ROW;
            a0 += wv.x * p0[0] + wv.y * p0[1] + wv.z * p0[2] + wv.w * p0[3];
            a1 += wv.x * p1[0] + wv.y * p1[1] + wv.z * p1[2] + wv.w * p1[3];
        }
        float xsv = s_xs[b];
        float2 st; st.x = (xsv + a0) / 128.f; st.y = (xsv + a1) / 128.f;
        ((float2*)out)[(boff + b) * (OUT / 2) + l] = st;
    }
}

extern "C" void kernel_launch(void* const* d_in, const int* in_sizes, int n_in,
                              void* d_out, int out_size, void* d_ws, size_t ws_size,
                              hipStream_t stream) {
    const float* x  = (const float*)d_in[0];
    const float* cf = (const float*)d_in[1];
    float* out = (float*)d_out;
    if (ws_size >= (size_t)CF_ELEMS * sizeof(unsigned short)) {
        unsigned short* cfb = (unsigned short*)d_ws;
        cvt_kernel<<<CF_ELEMS / 4 / 256, 256, 0, stream>>>((const float4*)cf, (ushort4*)cfb);
        kan_mfma<<<BATCH / MT, 256, 0, stream>>>(x, cfb, out);
    } else {
        kan_valu<<<BATCH / 16, 256, 0, stream>>>(x, cf, out);
    }
}

// Round 5
// 75.584 us; speedup vs baseline: 2.3434x; 1.1302x over previous
//
#include <hip/hip_runtime.h>

#define BATCH 8192
#define IN 128
#define OUT 128
#define NB 18
#define ROW (IN * NB)          // 2304
#define CF_ELEMS (OUT * ROW)   // 294912
#define MT 32                  // batch rows per block
#define AROW 296               // 288 + 8 bf16 pad per A-row
#define NCHG 4                 // K-chunks per K-group (2 groups x 4 x 288 = 2304)

typedef short  bf16x8 __attribute__((ext_vector_type(8)));
typedef float  f32x16 __attribute__((ext_vector_type(16)));

static __device__ __forceinline__ unsigned short f2bf(float f) {
    union { float f; unsigned u; } v; v.f = f;
    unsigned r = v.u + 0x7fffu + ((v.u >> 16) & 1u);   // RNE
    return (unsigned short)(r >> 16);
}
static __device__ __forceinline__ bf16x8 as_bf16x8(uint4 v) {
    union { uint4 u; bf16x8 b; } x; x.u = v; return x.b;
}
static __device__ __forceinline__ float fast_tanh(float v) {
    // 1 - 2/(e^{2v}+1): v_exp + v_rcp, |err| ~1e-6; inf/0 endpoints -> +/-1 exactly
    float e = __expf(2.0f * v);
    return 1.0f - 2.0f * __builtin_amdgcn_rcpf(e + 1.0f);
}

// cf fp32 [o][k] -> cfb2 bf16 tiled [k>>3][o][k&7]: one wave-load of B-fragments
// becomes two contiguous 512B segments instead of 32 scattered lines.
__global__ __launch_bounds__(256) void cvt_kernel(const float* __restrict__ cf,
                                                  unsigned short* __restrict__ cfb2) {
    int tid = blockIdx.x * 256 + threadIdx.x;   // 0 .. 36863
    int o  = tid & 127;
    int kb = tid >> 7;                          // k-octet 0..287
    const float4* src = (const float4*)(cf + o * ROW + kb * 8);
    float4 a = src[0], b = src[1];
    uint4 pk;
    pk.x = (unsigned)f2bf(a.x) | ((unsigned)f2bf(a.y) << 16);
    pk.y = (unsigned)f2bf(a.z) | ((unsigned)f2bf(a.w) << 16);
    pk.z = (unsigned)f2bf(b.x) | ((unsigned)f2bf(b.y) << 16);
    pk.w = (unsigned)f2bf(b.z) | ((unsigned)f2bf(b.w) << 16);
    ((uint4*)cfb2)[tid] = pk;                   // fully coalesced store
}

__global__ __launch_bounds__(512, 2) void kan_mfma(const float* __restrict__ x,
                                                   const unsigned short* __restrict__ cfb2,
                                                   float* __restrict__ out) {
    __shared__ unsigned short sA[2][MT][AROW];  // 37.9 KB: per-K-group basis tiles
    __shared__ float sbuf[MT][128];             // 16 KB: x-stage, then C-reduction
    __shared__ float s_xsp[2][MT];

    const int t  = threadIdx.x;
    const int g  = t >> 8;          // K-group 0/1
    const int tg = t & 255;
    const int w4 = (t >> 6) & 3;    // N-slice
    const int l  = t & 63;
    const int b0 = blockIdx.x * MT;
    const int n0 = w4 << 5;
    const int ab = tg >> 3;         // A-build row 0..31
    const int iq = tg & 7;
    const int h  = l >> 5;          // k-octet half
    const int am = l & 31;

    // ---- stage x[b0..b0+31][*] -> sbuf (coalesced float4) ----
    {
        const float4* xp = (const float4*)(x + b0 * IN);
        float4* sx4 = (float4*)&sbuf[0][0];
        sx4[t]       = xp[t];
        sx4[t + 512] = xp[t + 512];
    }

    f32x16 acc;
    #pragma unroll
    for (int r = 0; r < 16; ++r) acc[r] = 0.f;
    float xs = 0.f;

    const uint4* bbase = (const uint4*)cfb2;    // [kb][o] 16B units
    const int o = n0 + am;

    for (int cl = 0; cl < NCHG; ++cl) {
        const int c = g * NCHG + cl;
        __syncthreads();            // staging (cl=0) / prior A-frag reads done

        // ---- A-build: 2 cells (b=ab, i=16c+iq, +8) into this group's tile ----
        #pragma unroll
        for (int hh = 0; hh < 2; ++hh) {
            int il = iq + (hh << 3);
            int i  = (c << 4) + il;
            float xt = fast_tanh(sbuf[ab][i]);
            xs += xt;
            float s = (xt + 1.0f) * 7.5f;       // (xt+1)/h, h=2/15
            int m = (int)s; m = m < 0 ? 0 : (m > 14 ? 14 : m);
            float u = s - (float)m, om = 1.f - u, u2 = u * u;
            float w0 = (1.f / 6.f) * om * om * om;
            float w1 = (2.f / 3.f) - u2 * (1.f - 0.5f * u);
            float w2 = (1.f / 6.f) + 0.5f * (u + u2 - u2 * u);
            float w3 = (1.f / 6.f) * u * u2;
            unsigned lo = (unsigned)f2bf(w0) | ((unsigned)f2bf(w1) << 16);
            unsigned hi = (unsigned)f2bf(w2) | ((unsigned)f2bf(w3) << 16);
            int odd = m & 1;
            unsigned t0 = odd ? (lo << 16) : lo;
            unsigned t1 = odd ? ((hi << 16) | (lo >> 16)) : hi;
            unsigned t2 = odd ? (hi >> 16) : 0u;
            int dq = m >> 1;
            unsigned* dst = (unsigned*)(&sA[g][ab][0]) + il * 9;
            #pragma unroll
            for (int j = 0; j < 9; ++j)
                dst[j] = (j == dq) ? t0 : (j == dq + 1) ? t1
                       : (j == dq + 2) ? t2 : 0u;
        }
        __syncthreads();

        // ---- 18 MFMA steps; B loads are 2x512B contiguous per wave ----
        #pragma unroll
        for (int s = 0; s < 18; ++s) {
            uint4 bv = bbase[(c * 36 + 2 * s + h) * 128 + o];
            uint4 av = *(const uint4*)(&sA[g][am][(s << 4) + (h << 3)]);
            acc = __builtin_amdgcn_mfma_f32_32x32x16_bf16(
                      as_bf16x8(av), as_bf16x8(bv), acc, 0, 0, 0);
        }
    }

    // ---- tanh partial sums: 8 consecutive lanes share (g, ab) ----
    xs += __shfl_down(xs, 4, 8);
    xs += __shfl_down(xs, 2, 8);
    xs += __shfl_down(xs, 1, 8);
    if (iq == 0) s_xsp[g][ab] = xs;

    // ---- K-group reduction via sbuf (x-stage is dead now) ----
    if (g == 1) {
        #pragma unroll
        for (int r = 0; r < 16; ++r) {
            int row = (r & 3) + ((r >> 2) << 3) + (h << 2);
            sbuf[row][n0 + am] = acc[r];
        }
    }
    __syncthreads();
    if (g == 0) {
        #pragma unroll
        for (int r = 0; r < 16; ++r) {
            int row = (r & 3) + ((r >> 2) << 3) + (h << 2);
            float v = acc[r] + sbuf[row][n0 + am] + s_xsp[0][row] + s_xsp[1][row];
            out[(b0 + row) * OUT + n0 + am] = v * (1.0f / 128.0f);
        }
    }
}

// ---------------- fallback (ws too small): R3's proven VALU kernel ----------------
__global__ __launch_bounds__(256, 2) void kan_valu(const float* __restrict__ x,
                                                   const float* __restrict__ cf,
                                                   float* __restrict__ out) {
    __shared__ float4        s_w[16][IN];
    __shared__ unsigned char s_m[16][IN];
    __shared__ float         s_xs[16];
    const int t = threadIdx.x;
    const int boff = blockIdx.x * 16;
    {
        const int b = t >> 4, il = t & 15;
        float xs = 0.f;
        #pragma unroll
        for (int k = 0; k < IN / 16; ++k) {
            int i = il + 16 * k;
            float xt = tanhf(x[(boff + b) * IN + i]);
            xs += xt;
            float s = (xt + 1.0f) * 7.5f;
            int m = (int)s; m = m < 0 ? 0 : (m > 14 ? 14 : m);
            float u = s - (float)m, om = 1.f - u, u2 = u * u;
            s_w[b][i] = make_float4((1.f/6.f)*om*om*om,
                                    (2.f/3.f) - u2*(1.f - 0.5f*u),
                                    (1.f/6.f) + 0.5f*(u + u2 - u2*u),
                                    (1.f/6.f)*u*u2);
            s_m[b][i] = (unsigned char)m;
        }
        for (int d = 8; d > 0; d >>= 1) xs += __shfl_down(xs, d, 16);
        if (il == 0) s_xs[b] = xs;
    }
    __syncthreads();
    const int w = t >> 6, l = t & 63;
    #pragma unroll
    for (int r = 0; r < 4; ++r) {
        const int b = w * 4 + r;
        float a0 = 0.f, a1 = 0.f;
        for (int i = 0; i < IN; ++i) {
            float4 wv = s_w[b][i];
            int m = (int)s_m[b][i];
            const float* p0 = cf + (2 * l) * ROW + i * NB + m;
            const float* p1 = p0 + ROW;
            a0 += wv.x * p0[0] + wv.y * p0[1] + wv.z * p0[2] + wv.w * p0[3];
            a1 += wv.x * p1[0] + wv.y * p1[1] + wv.z * p1[2] + wv.w * p1[3];
        }
        float xsv = s_xs[b];
        float2 st; st.x = (xsv + a0) / 128.f; st.y = (xsv + a1) / 128.f;
        ((float2*)out)[(boff + b) * (OUT / 2) + l] = st;
    }
}

extern "C" void kernel_launch(void* const* d_in, const int* in_sizes, int n_in,
                              void* d_out, int out_size, void* d_ws, size_t ws_size,
                              hipStream_t stream) {
    const float* x  = (const float*)d_in[0];
    const float* cf = (const float*)d_in[1];
    float* out = (float*)d_out;
    if (ws_size >= (size_t)CF_ELEMS * sizeof(unsigned short)) {
        unsigned short* cfb2 = (unsigned short*)d_ws;
        cvt_kernel<<<CF_ELEMS / 8 / 256, 256, 0, stream>>>(cf, cfb2);
        kan_mfma<<<BATCH / MT, 512, 0, stream>>>(x, cfb2, out);
    } else {
        kan_valu<<<BATCH / 16, 256, 0, stream>>>(x, cf, out);
    }
}

// Round 6
// 69.067 us; speedup vs baseline: 2.5645x; 1.0944x over previous
//
#include <hip/hip_runtime.h>

#define BATCH 8192
#define IN 128
#define OUT 128
#define NB 18
#define ROW (IN * NB)          // 2304
#define CF_ELEMS (OUT * ROW)   // 294912
#define MT 32                  // batch rows per block
#define NCHG 4                 // K-chunks per K-group (2 groups x 4 x 288 = 2304)

typedef short  bf16x8 __attribute__((ext_vector_type(8)));
typedef float  f32x16 __attribute__((ext_vector_type(16)));

static __device__ __forceinline__ unsigned short f2bf(float f) {
    union { float f; unsigned u; } v; v.f = f;
    unsigned r = v.u + 0x7fffu + ((v.u >> 16) & 1u);   // RNE
    return (unsigned short)(r >> 16);
}
static __device__ __forceinline__ bf16x8 as_bf16x8(uint4 v) {
    union { uint4 u; bf16x8 b; } x; x.u = v; return x.b;
}
static __device__ __forceinline__ float fast_tanh(float v) {
    float e = __expf(2.0f * v);
    return 1.0f - 2.0f * __builtin_amdgcn_rcpf(e + 1.0f);
}

// cf fp32 [o][k] -> cfb2 bf16 tiled [k>>3][o][k&7]
__global__ __launch_bounds__(256) void cvt_kernel(const float* __restrict__ cf,
                                                  unsigned short* __restrict__ cfb2) {
    int tid = blockIdx.x * 256 + threadIdx.x;
    int o  = tid & 127;
    int kb = tid >> 7;
    const float4* src = (const float4*)(cf + o * ROW + kb * 8);
    float4 a = src[0], b = src[1];
    uint4 pk;
    pk.x = (unsigned)f2bf(a.x) | ((unsigned)f2bf(a.y) << 16);
    pk.y = (unsigned)f2bf(a.z) | ((unsigned)f2bf(a.w) << 16);
    pk.z = (unsigned)f2bf(b.x) | ((unsigned)f2bf(b.y) << 16);
    pk.w = (unsigned)f2bf(b.z) | ((unsigned)f2bf(b.w) << 16);
    ((uint4*)cfb2)[tid] = pk;
}

__global__ __launch_bounds__(512, 2) void kan_mfma(const float* __restrict__ x,
                                                   const unsigned short* __restrict__ cfb2,
                                                   float* __restrict__ out) {
    // A-tile transposed: [group][3 bufs][granule 0..35][row*4 + dw]
    // granule = 4 dwords = 8 k. MFMA read = contiguous 512B per half-wave.
    __shared__ unsigned sAT[2][3][36][128];   // 108 KB
    __shared__ float sbuf[MT][132];           // 16.9 KB x-stage (pad: 132%32=4 -> conflict-free)
    __shared__ float s_xsp[2][MT];

    const int t  = threadIdx.x;
    const int g  = t >> 8;          // K-group 0/1
    const int tg = t & 255;
    const int w4 = (t >> 6) & 3;    // N-slice
    const int l  = t & 63;
    const int b0 = blockIdx.x * MT;
    const int n0 = w4 << 5;
    const int ab = tg >> 3;         // A-build row 0..31
    const int iq = tg & 7;
    const int h  = l >> 5;          // k-octet half
    const int am = l & 31;

    // ---- stage x (coalesced float4, 16B-aligned: 132*4B = 33*16B) ----
    {
        const float4* xp = (const float4*)(x + b0 * IN);
        int i0 = t;
        *(float4*)&sbuf[i0 >> 5][(i0 & 31) << 2] = xp[i0];
        int i1 = t + 512;
        *(float4*)&sbuf[i1 >> 5][(i1 & 31) << 2] = xp[i1];
    }
    __syncthreads();

    f32x16 accA, accB;
    #pragma unroll
    for (int r = 0; r < 16; ++r) { accA[r] = 0.f; accB[r] = 0.f; }
    float xs = 0.f;

    const uint4* bbase = (const uint4*)cfb2;
    const int o = n0 + am;

    // ---- A-build for chunk c into buffer nb ----
    auto build = [&](int c, int nb) {
        unsigned* tile = &sAT[g][nb][0][0];
        #pragma unroll
        for (int hh = 0; hh < 2; ++hh) {
            int il = iq + (hh << 3);
            int i  = (c << 4) + il;
            float xt = fast_tanh(sbuf[ab][i]);
            xs += xt;
            float s = (xt + 1.0f) * 7.5f;
            int m = (int)s; m = m < 0 ? 0 : (m > 14 ? 14 : m);
            float u = s - (float)m, om = 1.f - u, u2 = u * u;
            float w0 = (1.f / 6.f) * om * om * om;
            float w1 = (2.f / 3.f) - u2 * (1.f - 0.5f * u);
            float w2 = (1.f / 6.f) + 0.5f * (u + u2 - u2 * u);
            float w3 = (1.f / 6.f) * u * u2;
            unsigned lo = (unsigned)f2bf(w0) | ((unsigned)f2bf(w1) << 16);
            unsigned hi = (unsigned)f2bf(w2) | ((unsigned)f2bf(w3) << 16);
            int odd = m & 1;
            unsigned t0 = odd ? (lo << 16) : lo;
            unsigned t1 = odd ? ((hi << 16) | (lo >> 16)) : hi;
            unsigned t2 = odd ? (hi >> 16) : 0u;
            int dq = m >> 1;
            int d0 = il * 9;
            #pragma unroll
            for (int j = 0; j < 9; ++j) {
                int d = d0 + j;
                unsigned v = (j == dq) ? t0 : (j == dq + 1) ? t1
                           : (j == dq + 2) ? t2 : 0u;
                tile[((d >> 2) << 7) + (ab << 2) + (d & 3)] = v;   // 2-way max
            }
        }
    };

    build(g * NCHG, 0);     // prologue: chunk 0 -> buf 0

    #pragma unroll
    for (int cc = 0; cc < NCHG; ++cc) {
        const int c = g * NCHG + cc;
        // B fragments for chunk c (global, issued before build VALU hides them)
        uint4 B[18];
        #pragma unroll
        for (int s = 0; s < 18; ++s)
            B[s] = bbase[(c * 36 + 2 * s + h) * 128 + o];
        if (cc + 1 < NCHG) build(c + 1, (cc + 1) % 3);
        __syncthreads();    // buf cc%3 complete for all waves
        const unsigned* tb = &sAT[g][cc % 3][0][0];
        #pragma unroll
        for (int s = 0; s < 18; ++s) {
            uint4 av = *(const uint4*)(tb + (((2 * s + h) << 7) + (am << 2)));
            if (s & 1) accB = __builtin_amdgcn_mfma_f32_32x32x16_bf16(
                                  as_bf16x8(av), as_bf16x8(B[s]), accB, 0, 0, 0);
            else       accA = __builtin_amdgcn_mfma_f32_32x32x16_bf16(
                                  as_bf16x8(av), as_bf16x8(B[s]), accA, 0, 0, 0);
        }
    }

    #pragma unroll
    for (int r = 0; r < 16; ++r) accA[r] += accB[r];

    // ---- tanh partial sums: 8 consecutive lanes share (g, ab) ----
    xs += __shfl_down(xs, 4, 8);
    xs += __shfl_down(xs, 2, 8);
    xs += __shfl_down(xs, 1, 8);
    if (iq == 0) s_xsp[g][ab] = xs;

    // ---- K-group reduction via sbuf (x-stage dead) ----
    if (g == 1) {
        #pragma unroll
        for (int r = 0; r < 16; ++r) {
            int row = (r & 3) + ((r >> 2) << 3) + (h << 2);
            sbuf[row][n0 + am] = accA[r];
        }
    }
    __syncthreads();
    if (g == 0) {
        #pragma unroll
        for (int r = 0; r < 16; ++r) {
            int row = (r & 3) + ((r >> 2) << 3) + (h << 2);
            float v = accA[r] + sbuf[row][n0 + am] + s_xsp[0][row] + s_xsp[1][row];
            out[(b0 + row) * OUT + n0 + am] = v * (1.0f / 128.0f);
        }
    }
}

// ---------------- fallback (ws too small): R3's proven VALU kernel ----------------
__global__ __launch_bounds__(256, 2) void kan_valu(const float* __restrict__ x,
                                                   const float* __restrict__ cf,
                                                   float* __restrict__ out) {
    __shared__ float4        s_w[16][IN];
    __shared__ unsigned char s_m[16][IN];
    __shared__ float         s_xs[16];
    const int t = threadIdx.x;
    const int boff = blockIdx.x * 16;
    {
        const int b = t >> 4, il = t & 15;
        float xs = 0.f;
        #pragma unroll
        for (int k = 0; k < IN / 16; ++k) {
            int i = il + 16 * k;
            float xt = tanhf(x[(boff + b) * IN + i]);
            xs += xt;
            float s = (xt + 1.0f) * 7.5f;
            int m = (int)s; m = m < 0 ? 0 : (m > 14 ? 14 : m);
            float u = s - (float)m, om = 1.f - u, u2 = u * u;
            s_w[b][i] = make_float4((1.f/6.f)*om*om*om,
                                    (2.f/3.f) - u2*(1.f - 0.5f*u),
                                    (1.f/6.f) + 0.5f*(u + u2 - u2*u),
                                    (1.f/6.f)*u*u2);
            s_m[b][i] = (unsigned char)m;
        }
        for (int d = 8; d > 0; d >>= 1) xs += __shfl_down(xs, d, 16);
        if (il == 0) s_xs[b] = xs;
    }
    __syncthreads();
    const int w = t >> 6, l = t & 63;
    #pragma unroll
    for (int r = 0; r < 4; ++r) {
        const int b = w * 4 + r;
        float a0 = 0.f, a1 = 0.f;
        for (int i = 0; i < IN; ++i) {
            float4 wv = s_w[b][i];
            int m = (int)s_m[b][i];
            const float* p0 = cf + (2 * l) * ROW + i * NB + m;
            const float* p1 = p0 + ROW;
            a0 += wv.x * p0[0] + wv.y * p0[1] + wv.z * p0[2] + wv.w * p0[3];
            a1 += wv.x * p1[0] + wv.y * p1[1] + wv.z * p1[2] + wv.w * p1[3];
        }
        float xsv = s_xs[b];
        float2 st; st.x = (xsv + a0) / 128.f; st.y = (xsv + a1) / 128.f;
        ((float2*)out)[(boff + b) * (OUT / 2) + l] = st;
    }
}

extern "C" void kernel_launch(void* const* d_in, const int* in_sizes, int n_in,
                              void* d_out, int out_size, void* d_ws, size_t ws_size,
                              hipStream_t stream) {
    const float* x  = (const float*)d_in[0];
    const float* cf = (const float*)d_in[1];
    float* out = (float*)d_out;
    if (ws_size >= (size_t)CF_ELEMS * sizeof(unsigned short)) {
        unsigned short* cfb2 = (unsigned short*)d_ws;
        cvt_kernel<<<CF_ELEMS / 8 / 256, 256, 0, stream>>>(cf, cfb2);
        kan_mfma<<<BATCH / MT, 512, 0, stream>>>(x, cfb2, out);
    } else {
        kan_valu<<<BATCH / 16, 256, 0, stream>>>(x, cf, out);
    }
}